// Round 2
// baseline (228.026 us; speedup 1.0000x reference)
//
#include <hip/hip_runtime.h>
#include <stdint.h>
#include <stddef.h>

#define B_ 2
#define H_ 8
#define S_ 2048
#define D_ 64
#define E_ 512
#define N3_ 1536
#define M_ (B_*S_)
#define K_ 512

typedef __attribute__((ext_vector_type(4))) float f32x4;
typedef __attribute__((ext_vector_type(8))) __bf16 bf16x8;
typedef __attribute__((ext_vector_type(4))) __bf16 bf16x4;

// XOR-swizzle within 128B rows: 16B-chunk index ^= (row & 7)  (involution)
static __device__ __forceinline__ int swz(int b) { return b ^ (((b >> 7) & 7) << 4); }

static __device__ __forceinline__ void gl_lds16(const void* g, void* l) {
    __builtin_amdgcn_global_load_lds((const __attribute__((address_space(1))) void*)g,
                                     (__attribute__((address_space(3))) void*)l, 16, 0, 0);
}

// ---------------- fp32 -> bf16 elementwise ----------------
__global__ void cvt_bf16_kernel(const float* __restrict__ in, __bf16* __restrict__ out, int n4) {
    int i = blockIdx.x * blockDim.x + threadIdx.x;
    if (i < n4) {
        float4 v = reinterpret_cast<const float4*>(in)[i];
        bf16x4 o;
        o[0] = (__bf16)v.x; o[1] = (__bf16)v.y; o[2] = (__bf16)v.z; o[3] = (__bf16)v.w;
        reinterpret_cast<bf16x4*>(out)[i] = o;
    }
}

// ---------------- fp32 [R][C] -> bf16 [C][R] ----------------
__global__ void transpose_cvt_kernel(const float* __restrict__ in, __bf16* __restrict__ out,
                                     int R, int C) {
    __shared__ float tile[32][33];
    int tc = blockIdx.x * 32, tr = blockIdx.y * 32;
    int lx = threadIdx.x & 31, ly = threadIdx.x >> 5;
    #pragma unroll
    for (int p = 0; p < 4; ++p) {
        int r = tr + ly + p * 8, c = tc + lx;
        if (r < R && c < C) tile[ly + p * 8][lx] = in[(size_t)r * C + c];
    }
    __syncthreads();
    #pragma unroll
    for (int p = 0; p < 4; ++p) {
        int oc = tc + ly + p * 8;
        int orow = tr + lx;
        if (oc < C && orow < R) out[(size_t)oc * R + orow] = (__bf16)tile[lx][ly + p * 8];
    }
}

// ---------------- bf16 [BH][S][64] -> [BH][64][S] ----------------
__global__ void transpose_v_kernel(const __bf16* __restrict__ v, __bf16* __restrict__ vt) {
    __shared__ __bf16 t[64][65];
    int bh = blockIdx.x >> 5;
    int s0 = (blockIdx.x & 31) << 6;
    int tid = threadIdx.x;
    const __bf16* src = v + ((size_t)bh * S_ + s0) * D_;
    #pragma unroll
    for (int p = 0; p < 2; ++p) {
        int idx = (p * 256 + tid) * 8;
        int r = idx >> 6, c = idx & 63;
        bf16x8 val = *reinterpret_cast<const bf16x8*>(src + (size_t)r * D_ + c);
        #pragma unroll
        for (int e = 0; e < 8; ++e) t[r][c + e] = val[e];
    }
    __syncthreads();
    __bf16* dst = vt + (size_t)bh * D_ * S_ + s0;
    #pragma unroll
    for (int p = 0; p < 16; ++p) {
        int idx = p * 256 + tid;
        int d = idx >> 6, s = idx & 63;
        dst[(size_t)d * S_ + s] = t[s][d];
    }
}

// ---------------- bf16 MFMA GEMM: C[M][N] = A[M][K] @ Bt[N][K]^T + bias ----------------
template<int MODE>
__global__ __launch_bounds__(256, 2) void gemm_kernel(
    const __bf16* __restrict__ A, const __bf16* __restrict__ Bt,
    const float* __restrict__ bias,
    void* __restrict__ o0, void* __restrict__ o1, void* __restrict__ o2,
    int M, int N, int K)
{
    __shared__ __align__(16) __bf16 lA[128 * 64];
    __shared__ __align__(16) __bf16 lB[128 * 64];
    const int tid = threadIdx.x;
    const int wave = tid >> 6, lane = tid & 63;
    const int wm = wave >> 1, wn = wave & 1;
    const int m0 = blockIdx.y * 128, n0 = blockIdx.x * 128;
    const int l15 = lane & 15, l4 = lane >> 4;

    f32x4 acc[4][4] = {};

    for (int k0 = 0; k0 < K; k0 += 64) {
        __syncthreads();
        #pragma unroll
        for (int p = 0; p < 4; ++p) {
            int base = p * 4096 + wave * 1024;
            int js = swz(base + lane * 16);
            int row = js >> 7, colb = js & 127;
            gl_lds16((const char*)A + ((size_t)(m0 + row) * K + k0) * 2 + colb, (char*)lA + base);
            gl_lds16((const char*)Bt + ((size_t)(n0 + row) * K + k0) * 2 + colb, (char*)lB + base);
        }
        __syncthreads();
        #pragma unroll
        for (int ks = 0; ks < 2; ++ks) {
            bf16x8 af[4], bfr[4];
            #pragma unroll
            for (int i = 0; i < 4; ++i) {
                af[i]  = *(const bf16x8*)((const char*)lA + swz(((wm * 64 + i * 16 + l15) << 7) + ks * 64 + (l4 << 4)));
                bfr[i] = *(const bf16x8*)((const char*)lB + swz(((wn * 64 + i * 16 + l15) << 7) + ks * 64 + (l4 << 4)));
            }
            #pragma unroll
            for (int i = 0; i < 4; ++i)
                #pragma unroll
                for (int j = 0; j < 4; ++j)
                    acc[i][j] = __builtin_amdgcn_mfma_f32_16x16x32_bf16(af[i], bfr[j], acc[i][j], 0, 0, 0);
        }
    }
    #pragma unroll
    for (int i = 0; i < 4; ++i) {
        int mg0 = m0 + wm * 64 + i * 16 + (l4 << 2);
        #pragma unroll
        for (int j = 0; j < 4; ++j) {
            int ng = n0 + wn * 64 + j * 16 + l15;
            float bv = bias[ng];
            #pragma unroll
            for (int r = 0; r < 4; ++r) {
                int m = mg0 + r;
                float val = acc[i][j][r] + bv;
                if (MODE == 0) {
                    int h = ng / 192, rr = ng % 192;
                    int which = rr >> 6, d = rr & 63;
                    int b = m >> 11, s = m & (S_ - 1);
                    if (which == 0) val *= 0.125f;
                    __bf16* dst = which == 0 ? (__bf16*)o0 : which == 1 ? (__bf16*)o1 : (__bf16*)o2;
                    dst[(((size_t)((b * H_ + h) * S_ + s)) << 6) + d] = (__bf16)val;
                } else {
                    ((float*)o0)[(size_t)m * N + ng] = val;
                }
            }
        }
    }
}

// ---------------- merged: bias GEMM blocks + flash-attn blocks ----------------
// blocks [0,512): (dist+path)@V streaming GEMM -> biaso fp32 [bh][S][64]
// blocks [512,1024): flash attention (no bias)  -> attno fp32 [bh][S][64]
#define NBIAS 512
__global__ __launch_bounds__(256, 4) void fused_kernel(
    const __bf16* __restrict__ q, const __bf16* __restrict__ k,
    const __bf16* __restrict__ vt,
    const float* __restrict__ dist, const float* __restrict__ path,
    float* __restrict__ attno, float* __restrict__ biaso)
{
    __shared__ __align__(16) __bf16 kl[64 * 64];
    __shared__ __align__(16) __bf16 vl[64 * 64];
    __shared__ __align__(16) __bf16 pl[4][16 * 64];
    const int tid = threadIdx.x, wave = tid >> 6, lane = tid & 63;
    const int l15 = lane & 15, l4 = lane >> 4;
    const int id = blockIdx.x;

    if (id < NBIAS) {
        // -------- bias GEMM: no LDS, no barriers, pure stream --------
        const int xcd = id & 7, j = id >> 3;
        const int bh = xcd * 2 + (j >> 5), m0 = (j & 31) << 6;
        const int row = m0 + wave * 16 + l15;
        const float* dp = dist + ((size_t)bh * S_ + row) * S_;
        const float* pp = path + ((size_t)bh * S_ + row) * S_;
        const __bf16* vtp = vt + (size_t)bh * D_ * S_;
        f32x4 acc[4] = {};
        #pragma unroll 2
        for (int k0 = 0; k0 < S_; k0 += 32) {
            int kc = k0 + (l4 << 3);
            float4 d0 = *(const float4*)(dp + kc), d1 = *(const float4*)(dp + kc + 4);
            float4 p0 = *(const float4*)(pp + kc), p1 = *(const float4*)(pp + kc + 4);
            bf16x8 a;
            a[0] = (__bf16)(d0.x + p0.x); a[1] = (__bf16)(d0.y + p0.y);
            a[2] = (__bf16)(d0.z + p0.z); a[3] = (__bf16)(d0.w + p0.w);
            a[4] = (__bf16)(d1.x + p1.x); a[5] = (__bf16)(d1.y + p1.y);
            a[6] = (__bf16)(d1.z + p1.z); a[7] = (__bf16)(d1.w + p1.w);
            #pragma unroll
            for (int n = 0; n < 4; ++n) {
                bf16x8 vf = *(const bf16x8*)(vtp + (size_t)(n * 16 + l15) * S_ + kc);
                acc[n] = __builtin_amdgcn_mfma_f32_16x16x32_bf16(a, vf, acc[n], 0, 0, 0);
            }
        }
        #pragma unroll
        for (int n = 0; n < 4; ++n)
            #pragma unroll
            for (int r = 0; r < 4; ++r)
                biaso[((size_t)bh * S_ + m0 + wave * 16 + (l4 << 2) + r) * D_ + n * 16 + l15] = acc[n][r];
        return;
    }

    // -------- flash attention (no bias) --------
    const int aid = id - NBIAS;
    const int xcd = aid & 7, j = aid >> 3;
    const int bh = xcd * 2 + (j >> 5);
    const int q0 = (j & 31) << 6;
    const int qrow = q0 + wave * 16 + l15;

    const __bf16* qp = q + ((size_t)bh * S_ + qrow) * D_;
    bf16x8 qf0 = *(const bf16x8*)(qp + (l4 << 3));
    bf16x8 qf1 = *(const bf16x8*)(qp + 32 + (l4 << 3));

    float m_run[4], l_run[4];
    f32x4 o_p[4] = {};
    #pragma unroll
    for (int r = 0; r < 4; ++r) { m_run[r] = -1e30f; l_run[r] = 0.f; }

    const char* kg = (const char*)(k + (size_t)bh * S_ * D_);
    const char* vg = (const char*)(vt + (size_t)bh * D_ * S_);

    for (int kt = 0; kt < S_; kt += 64) {
        __syncthreads();
        #pragma unroll
        for (int p = 0; p < 2; ++p) {
            int base = p * 4096 + wave * 1024;
            int js = swz(base + lane * 16);
            int row = js >> 7, colb = js & 127;
            gl_lds16(kg + ((size_t)(kt + row) * D_) * 2 + colb, (char*)kl + base);
            gl_lds16(vg + ((size_t)row * S_ + kt) * 2 + colb, (char*)vl + base);
        }
        __syncthreads();

        f32x4 lg[4] = {};
        #pragma unroll
        for (int ks = 0; ks < 2; ++ks) {
            bf16x8 qa = ks ? qf1 : qf0;
            #pragma unroll
            for (int n = 0; n < 4; ++n) {
                bf16x8 kf = *(const bf16x8*)((const char*)kl + swz(((n * 16 + l15) << 7) + ks * 64 + (l4 << 4)));
                lg[n] = __builtin_amdgcn_mfma_f32_16x16x32_bf16(qa, kf, lg[n], 0, 0, 0);
            }
        }
        float scale[4], rsum[4], pe[4][4];
        #pragma unroll
        for (int r = 0; r < 4; ++r) {
            float t = fmaxf(fmaxf(lg[0][r], lg[1][r]), fmaxf(lg[2][r], lg[3][r]));
            t = fmaxf(t, __shfl_xor(t, 1));
            t = fmaxf(t, __shfl_xor(t, 2));
            t = fmaxf(t, __shfl_xor(t, 4));
            t = fmaxf(t, __shfl_xor(t, 8));
            float mnew = fmaxf(m_run[r], t);
            scale[r] = __expf(m_run[r] - mnew);
            m_run[r] = mnew;
            rsum[r] = 0.f;
        }
        #pragma unroll
        for (int n = 0; n < 4; ++n)
            #pragma unroll
            for (int r = 0; r < 4; ++r) {
                pe[n][r] = __expf(lg[n][r] - m_run[r]);
                rsum[r] += pe[n][r];
            }
        #pragma unroll
        for (int r = 0; r < 4; ++r) {
            float s = rsum[r];
            s += __shfl_xor(s, 1);
            s += __shfl_xor(s, 2);
            s += __shfl_xor(s, 4);
            s += __shfl_xor(s, 8);
            l_run[r] = l_run[r] * scale[r] + s;
        }
        #pragma unroll
        for (int n = 0; n < 4; ++n)
            #pragma unroll
            for (int r = 0; r < 4; ++r)
                o_p[n][r] *= scale[r];
        char* pb = (char*)&pl[wave][0];
        #pragma unroll
        for (int n = 0; n < 4; ++n)
            #pragma unroll
            for (int r = 0; r < 4; ++r) {
                int prow = (l4 << 2) + r, pcol = n * 16 + l15;
                *(__bf16*)(pb + swz((prow << 7) + pcol * 2)) = (__bf16)pe[n][r];
            }
        #pragma unroll
        for (int ks = 0; ks < 2; ++ks) {
            bf16x8 pa = *(const bf16x8*)((const char*)pb + swz((l15 << 7) + ks * 64 + (l4 << 4)));
            #pragma unroll
            for (int n = 0; n < 4; ++n) {
                bf16x8 vf = *(const bf16x8*)((const char*)vl + swz(((n * 16 + l15) << 7) + ks * 64 + (l4 << 4)));
                o_p[n] = __builtin_amdgcn_mfma_f32_16x16x32_bf16(pa, vf, o_p[n], 0, 0, 0);
            }
        }
    }
    #pragma unroll
    for (int r = 0; r < 4; ++r) {
        int s = q0 + wave * 16 + (l4 << 2) + r;
        float inv = 1.f / l_run[r];
        float* dst = attno + ((size_t)bh * S_ + s) * D_;
        #pragma unroll
        for (int n = 0; n < 4; ++n)
            dst[n * 16 + l15] = o_p[n][r] * inv;
    }
}

// ---------------- combine: bf16(attn + bias), [bh][s][d] -> [b][s][h*64+d] ----------------
__global__ void combine_kernel(const float* __restrict__ a, const float* __restrict__ b,
                               __bf16* __restrict__ out) {
    int i = blockIdx.x * blockDim.x + threadIdx.x;   // 262144 threads, 8 elems each
    size_t off = (size_t)i * 8;
    int d = (int)(off & 63);
    int s = (int)((off >> 6) & (S_ - 1));
    int bh = (int)(off >> 17);
    f32x4 a0 = ((const f32x4*)(a + off))[0], a1 = ((const f32x4*)(a + off))[1];
    f32x4 b0 = ((const f32x4*)(b + off))[0], b1 = ((const f32x4*)(b + off))[1];
    bf16x8 o;
    o[0] = (__bf16)(a0[0] + b0[0]); o[1] = (__bf16)(a0[1] + b0[1]);
    o[2] = (__bf16)(a0[2] + b0[2]); o[3] = (__bf16)(a0[3] + b0[3]);
    o[4] = (__bf16)(a1[0] + b1[0]); o[5] = (__bf16)(a1[1] + b1[1]);
    o[6] = (__bf16)(a1[2] + b1[2]); o[7] = (__bf16)(a1[3] + b1[3]);
    int bb = bh >> 3, h = bh & 7;
    *(bf16x8*)(out + ((size_t)(bb * S_ + s) * E_) + h * D_ + d) = o;
}

extern "C" void kernel_launch(void* const* d_in, const int* in_sizes, int n_in,
                              void* d_out, int out_size, void* d_ws, size_t ws_size,
                              hipStream_t stream) {
    (void)in_sizes; (void)n_in; (void)out_size; (void)ws_size;
    const float* x      = (const float*)d_in[0];
    const float* dist   = (const float*)d_in[1];
    const float* path   = (const float*)d_in[2];
    const float* qkv_w  = (const float*)d_in[3];
    const float* qkv_b  = (const float*)d_in[4];
    const float* o_w    = (const float*)d_in[5];
    const float* o_b    = (const float*)d_in[6];
    float* out = (float*)d_out;

    char* ws = (char*)d_ws;
    // layout (MB): [0,4) xb | [4,8) vb | [0,8) attno (overlay, after xb/vb dead)
    //              [8,12) qb | [12,16) kb | [16,20) vtb
    //              [20,21.5) qkv_wT | [21.5,22) o_wT | [22,30) biaso | [30,34) valsb
    __bf16* xb     = (__bf16*)(ws);
    __bf16* vb     = (__bf16*)(ws + (4  << 20));
    float*  attno  = (float*) (ws);
    __bf16* qb     = (__bf16*)(ws + (8  << 20));
    __bf16* kb     = (__bf16*)(ws + (12 << 20));
    __bf16* vtb    = (__bf16*)(ws + (16 << 20));
    __bf16* qkv_wT = (__bf16*)(ws + (20 << 20));
    __bf16* o_wT   = (__bf16*)(ws + (20 << 20) + (3 << 19));
    float*  biaso  = (float*) (ws + (22 << 20));
    __bf16* valsb  = (__bf16*)(ws + (30 << 20));

    cvt_bf16_kernel<<<(M_ * K_ / 4 + 255) / 256, 256, 0, stream>>>(x, xb, M_ * K_ / 4);
    transpose_cvt_kernel<<<dim3(N3_ / 32, K_ / 32), 256, 0, stream>>>(qkv_w, qkv_wT, K_, N3_);
    transpose_cvt_kernel<<<dim3(E_ / 32, E_ / 32), 256, 0, stream>>>(o_w, o_wT, E_, E_);
    gemm_kernel<0><<<dim3(N3_ / 128, M_ / 128), 256, 0, stream>>>(xb, qkv_wT, qkv_b, qb, kb, vb, M_, N3_, K_);
    transpose_v_kernel<<<B_ * H_ * (S_ / 64), 256, 0, stream>>>(vb, vtb);
    fused_kernel<<<NBIAS + 512, 256, 0, stream>>>(qb, kb, vtb, dist, path, attno, biaso);
    combine_kernel<<<(B_ * H_ * S_ * D_ / 8) / 256, 256, 0, stream>>>(attno, biaso, valsb);
    gemm_kernel<1><<<dim3(E_ / 128, M_ / 128), 256, 0, stream>>>(valsb, o_wT, o_b, out, nullptr, nullptr, M_, E_, K_);
}

// Round 3
// 192.590 us; speedup vs baseline: 1.1840x; 1.1840x over previous
//
#include <hip/hip_runtime.h>
#include <stdint.h>
#include <stddef.h>

#define B_ 2
#define H_ 8
#define S_ 2048
#define D_ 64
#define E_ 512
#define N3_ 1536
#define M_ (B_*S_)
#define K_ 512

typedef __attribute__((ext_vector_type(4))) float f32x4;
typedef __attribute__((ext_vector_type(8))) __bf16 bf16x8;
typedef __attribute__((ext_vector_type(4))) __bf16 bf16x4;

// XOR-swizzle within 128B rows: 16B-chunk index ^= (row & 7)  (involution)
static __device__ __forceinline__ int swz(int b) { return b ^ (((b >> 7) & 7) << 4); }

static __device__ __forceinline__ void gl_lds16(const void* g, void* l) {
    __builtin_amdgcn_global_load_lds((const __attribute__((address_space(1))) void*)g,
                                     (__attribute__((address_space(3))) void*)l, 16, 0, 0);
}

// ---------------- fp32 -> bf16 elementwise ----------------
__global__ void cvt_bf16_kernel(const float* __restrict__ in, __bf16* __restrict__ out, int n4) {
    int i = blockIdx.x * blockDim.x + threadIdx.x;
    if (i < n4) {
        float4 v = reinterpret_cast<const float4*>(in)[i];
        bf16x4 o;
        o[0] = (__bf16)v.x; o[1] = (__bf16)v.y; o[2] = (__bf16)v.z; o[3] = (__bf16)v.w;
        reinterpret_cast<bf16x4*>(out)[i] = o;
    }
}

// ---------------- fp32 [R][C] -> bf16 [C][R] ----------------
__global__ void transpose_cvt_kernel(const float* __restrict__ in, __bf16* __restrict__ out,
                                     int R, int C) {
    __shared__ float tile[32][33];
    int tc = blockIdx.x * 32, tr = blockIdx.y * 32;
    int lx = threadIdx.x & 31, ly = threadIdx.x >> 5;
    #pragma unroll
    for (int p = 0; p < 4; ++p) {
        int r = tr + ly + p * 8, c = tc + lx;
        if (r < R && c < C) tile[ly + p * 8][lx] = in[(size_t)r * C + c];
    }
    __syncthreads();
    #pragma unroll
    for (int p = 0; p < 4; ++p) {
        int oc = tc + ly + p * 8;
        int orow = tr + lx;
        if (oc < C && orow < R) out[(size_t)oc * R + orow] = (__bf16)tile[lx][ly + p * 8];
    }
}

// ---------------- bf16 [BH][S][64] -> [BH][64][S] ----------------
__global__ void transpose_v_kernel(const __bf16* __restrict__ v, __bf16* __restrict__ vt) {
    __shared__ __bf16 t[64][65];
    int bh = blockIdx.x >> 5;
    int s0 = (blockIdx.x & 31) << 6;
    int tid = threadIdx.x;
    const __bf16* src = v + ((size_t)bh * S_ + s0) * D_;
    #pragma unroll
    for (int p = 0; p < 2; ++p) {
        int idx = (p * 256 + tid) * 8;
        int r = idx >> 6, c = idx & 63;
        bf16x8 val = *reinterpret_cast<const bf16x8*>(src + (size_t)r * D_ + c);
        #pragma unroll
        for (int e = 0; e < 8; ++e) t[r][c + e] = val[e];
    }
    __syncthreads();
    __bf16* dst = vt + (size_t)bh * D_ * S_ + s0;
    #pragma unroll
    for (int p = 0; p < 16; ++p) {
        int idx = p * 256 + tid;
        int d = idx >> 6, s = idx & 63;
        dst[(size_t)d * S_ + s] = t[s][d];
    }
}

// ---------------- bf16 MFMA GEMM: C[M][N] = A[M][K] @ Bt[N][K]^T + bias ----------------
template<int MODE>
__global__ __launch_bounds__(256, 2) void gemm_kernel(
    const __bf16* __restrict__ A, const __bf16* __restrict__ Bt,
    const float* __restrict__ bias,
    void* __restrict__ o0, void* __restrict__ o1, void* __restrict__ o2,
    int M, int N, int K)
{
    __shared__ __align__(16) __bf16 lA[128 * 64];
    __shared__ __align__(16) __bf16 lB[128 * 64];
    const int tid = threadIdx.x;
    const int wave = tid >> 6, lane = tid & 63;
    const int wm = wave >> 1, wn = wave & 1;
    const int m0 = blockIdx.y * 128, n0 = blockIdx.x * 128;
    const int l15 = lane & 15, l4 = lane >> 4;

    f32x4 acc[4][4] = {};

    for (int k0 = 0; k0 < K; k0 += 64) {
        __syncthreads();
        #pragma unroll
        for (int p = 0; p < 4; ++p) {
            int base = p * 4096 + wave * 1024;
            int js = swz(base + lane * 16);
            int row = js >> 7, colb = js & 127;
            gl_lds16((const char*)A + ((size_t)(m0 + row) * K + k0) * 2 + colb, (char*)lA + base);
            gl_lds16((const char*)Bt + ((size_t)(n0 + row) * K + k0) * 2 + colb, (char*)lB + base);
        }
        __syncthreads();
        #pragma unroll
        for (int ks = 0; ks < 2; ++ks) {
            bf16x8 af[4], bfr[4];
            #pragma unroll
            for (int i = 0; i < 4; ++i) {
                af[i]  = *(const bf16x8*)((const char*)lA + swz(((wm * 64 + i * 16 + l15) << 7) + ks * 64 + (l4 << 4)));
                bfr[i] = *(const bf16x8*)((const char*)lB + swz(((wn * 64 + i * 16 + l15) << 7) + ks * 64 + (l4 << 4)));
            }
            #pragma unroll
            for (int i = 0; i < 4; ++i)
                #pragma unroll
                for (int j = 0; j < 4; ++j)
                    acc[i][j] = __builtin_amdgcn_mfma_f32_16x16x32_bf16(af[i], bfr[j], acc[i][j], 0, 0, 0);
        }
    }
    #pragma unroll
    for (int i = 0; i < 4; ++i) {
        int mg0 = m0 + wm * 64 + i * 16 + (l4 << 2);
        #pragma unroll
        for (int j = 0; j < 4; ++j) {
            int ng = n0 + wn * 64 + j * 16 + l15;
            float bv = bias[ng];
            #pragma unroll
            for (int r = 0; r < 4; ++r) {
                int m = mg0 + r;
                float val = acc[i][j][r] + bv;
                if (MODE == 0) {
                    int h = ng / 192, rr = ng % 192;
                    int which = rr >> 6, d = rr & 63;
                    int b = m >> 11, s = m & (S_ - 1);
                    if (which == 0) val *= 0.125f;
                    __bf16* dst = which == 0 ? (__bf16*)o0 : which == 1 ? (__bf16*)o1 : (__bf16*)o2;
                    dst[(((size_t)((b * H_ + h) * S_ + s)) << 6) + d] = (__bf16)val;
                } else {
                    ((float*)o0)[(size_t)m * N + ng] = val;
                }
            }
        }
    }
}

// ---------------- fused attention + bias@V, software-pipelined ----------------
// grid: B*H*(S/64) = 512; 4 waves x 16 q-rows. XCD-grouped: 2 heads per XCD.
__global__ __launch_bounds__(256, 2) void attn_kernel(
    const __bf16* __restrict__ q, const __bf16* __restrict__ k,
    const __bf16* __restrict__ vt,
    const float* __restrict__ dist, const float* __restrict__ path,
    __bf16* __restrict__ vals)
{
    __shared__ __align__(16) __bf16 kl[2][64 * 64];
    __shared__ __align__(16) __bf16 vl[2][64 * 64];
    __shared__ __align__(16) __bf16 pl[4][16 * 64];
    const int tid = threadIdx.x, wave = tid >> 6, lane = tid & 63;
    const int l15 = lane & 15, l4 = lane >> 4;
    const int id = blockIdx.x;
    const int xcd = id & 7, j = id >> 3;
    const int bh = xcd * 2 + (j >> 5);          // 2 heads per XCD -> K/V L2-resident
    const int q0 = (j & 31) << 6;
    const int b = bh >> 3, h = bh & 7;
    const int qrow = q0 + wave * 16 + l15;

    const __bf16* qp = q + ((size_t)bh * S_ + qrow) * D_;
    bf16x8 qf0 = *(const bf16x8*)(qp + (l4 << 3));
    bf16x8 qf1 = *(const bf16x8*)(qp + 32 + (l4 << 3));

    const float* dp = dist + ((size_t)bh * S_ + qrow) * S_;
    const float* pp = path + ((size_t)bh * S_ + qrow) * S_;

    const char* kg = (const char*)(k + (size_t)bh * S_ * D_);
    const char* vg = (const char*)(vt + (size_t)bh * D_ * S_);

    auto STAGE = [&](int kt, int buf) {
        #pragma unroll
        for (int p = 0; p < 2; ++p) {
            int base = p * 4096 + wave * 1024;
            int js = swz(base + lane * 16);
            int row = js >> 7, colb = js & 127;
            gl_lds16(kg + ((size_t)(kt + row) * D_) * 2 + colb, (char*)kl[buf] + base);
            gl_lds16(vg + ((size_t)row * S_ + kt) * 2 + colb, (char*)vl[buf] + base);
        }
    };
    float4 fb[8];  // raw next-tile bias: [0..3] dist(ks0 lo,hi, ks1 lo,hi), [4..7] path
    auto BLOAD = [&](int kt) {
        #pragma unroll
        for (int ks = 0; ks < 2; ++ks) {
            int kc = kt + ks * 32 + (l4 << 3);
            fb[ks * 2 + 0] = *(const float4*)(dp + kc);
            fb[ks * 2 + 1] = *(const float4*)(dp + kc + 4);
            fb[4 + ks * 2 + 0] = *(const float4*)(pp + kc);
            fb[4 + ks * 2 + 1] = *(const float4*)(pp + kc + 4);
        }
    };

    float m_run[4], l_run[4];
    f32x4 o_p[4] = {}, o_b[4] = {};
    #pragma unroll
    for (int r = 0; r < 4; ++r) { m_run[r] = -1e30f; l_run[r] = 0.f; }

    // prologue: stage tile 0
    STAGE(0, 0);
    BLOAD(0);
    __syncthreads();   // drains vmcnt(0) too

    int cur = 0;
    for (int kt = 0; kt < S_; kt += 64) {
        // consume raw bias regs for THIS tile (frees fb for next prefetch)
        bf16x8 ba[2];
        #pragma unroll
        for (int ks = 0; ks < 2; ++ks) {
            float4 d0 = fb[ks * 2], d1 = fb[ks * 2 + 1];
            float4 p0 = fb[4 + ks * 2], p1 = fb[4 + ks * 2 + 1];
            ba[ks][0] = (__bf16)(d0.x + p0.x); ba[ks][1] = (__bf16)(d0.y + p0.y);
            ba[ks][2] = (__bf16)(d0.z + p0.z); ba[ks][3] = (__bf16)(d0.w + p0.w);
            ba[ks][4] = (__bf16)(d1.x + p1.x); ba[ks][5] = (__bf16)(d1.y + p1.y);
            ba[ks][6] = (__bf16)(d1.z + p1.z); ba[ks][7] = (__bf16)(d1.w + p1.w);
        }
        // prefetch tile t+1 (memory overlaps compute below)
        int ktn = (kt + 64 < S_) ? kt + 64 : kt;
        STAGE(ktn, cur ^ 1);
        BLOAD(ktn);

        // ---- compute on buf[cur] ----
        f32x4 lg[4] = {};
        #pragma unroll
        for (int ks = 0; ks < 2; ++ks) {
            bf16x8 qa = ks ? qf1 : qf0;
            #pragma unroll
            for (int n = 0; n < 4; ++n) {
                bf16x8 kf = *(const bf16x8*)((const char*)kl[cur] + swz(((n * 16 + l15) << 7) + ks * 64 + (l4 << 4)));
                lg[n] = __builtin_amdgcn_mfma_f32_16x16x32_bf16(qa, kf, lg[n], 0, 0, 0);
            }
        }
        // bias @ V (independent of softmax chain)
        #pragma unroll
        for (int ks = 0; ks < 2; ++ks)
            #pragma unroll
            for (int n = 0; n < 4; ++n) {
                bf16x8 vf = *(const bf16x8*)((const char*)vl[cur] + swz(((n * 16 + l15) << 7) + ks * 64 + (l4 << 4)));
                o_b[n] = __builtin_amdgcn_mfma_f32_16x16x32_bf16(ba[ks], vf, o_b[n], 0, 0, 0);
            }
        // online softmax
        float scale[4], rsum[4], pe[4][4];
        #pragma unroll
        for (int r = 0; r < 4; ++r) {
            float t = fmaxf(fmaxf(lg[0][r], lg[1][r]), fmaxf(lg[2][r], lg[3][r]));
            t = fmaxf(t, __shfl_xor(t, 1));
            t = fmaxf(t, __shfl_xor(t, 2));
            t = fmaxf(t, __shfl_xor(t, 4));
            t = fmaxf(t, __shfl_xor(t, 8));
            float mnew = fmaxf(m_run[r], t);
            scale[r] = __expf(m_run[r] - mnew);
            m_run[r] = mnew;
            rsum[r] = 0.f;
        }
        #pragma unroll
        for (int n = 0; n < 4; ++n)
            #pragma unroll
            for (int r = 0; r < 4; ++r) {
                pe[n][r] = __expf(lg[n][r] - m_run[r]);
                rsum[r] += pe[n][r];
            }
        #pragma unroll
        for (int r = 0; r < 4; ++r) {
            float s = rsum[r];
            s += __shfl_xor(s, 1);
            s += __shfl_xor(s, 2);
            s += __shfl_xor(s, 4);
            s += __shfl_xor(s, 8);
            l_run[r] = l_run[r] * scale[r] + s;
        }
        #pragma unroll
        for (int n = 0; n < 4; ++n)
            #pragma unroll
            for (int r = 0; r < 4; ++r)
                o_p[n][r] *= scale[r];
        // P -> per-wave swizzled LDS -> A-frag layout (same-wave, lgkmcnt-ordered)
        char* pb = (char*)&pl[wave][0];
        #pragma unroll
        for (int n = 0; n < 4; ++n)
            #pragma unroll
            for (int r = 0; r < 4; ++r) {
                int prow = (l4 << 2) + r, pcol = n * 16 + l15;
                *(__bf16*)(pb + swz((prow << 7) + pcol * 2)) = (__bf16)pe[n][r];
            }
        #pragma unroll
        for (int ks = 0; ks < 2; ++ks) {
            bf16x8 pa = *(const bf16x8*)((const char*)pb + swz((l15 << 7) + ks * 64 + (l4 << 4)));
            #pragma unroll
            for (int n = 0; n < 4; ++n) {
                bf16x8 vf = *(const bf16x8*)((const char*)vl[cur] + swz(((n * 16 + l15) << 7) + ks * 64 + (l4 << 4)));
                o_p[n] = __builtin_amdgcn_mfma_f32_16x16x32_bf16(pa, vf, o_p[n], 0, 0, 0);
            }
        }
        __syncthreads();   // drains vmcnt(0): stage(t+1) + bias(t+1) complete
        cur ^= 1;
    }
    #pragma unroll
    for (int r = 0; r < 4; ++r) {
        int s = q0 + wave * 16 + (l4 << 2) + r;
        float inv = 1.f / l_run[r];
        __bf16* dst = vals + (size_t)(b * S_ + s) * E_ + h * D_;
        #pragma unroll
        for (int n = 0; n < 4; ++n) {
            int d = n * 16 + l15;
            dst[d] = (__bf16)(o_p[n][r] * inv + o_b[n][r]);
        }
    }
}

extern "C" void kernel_launch(void* const* d_in, const int* in_sizes, int n_in,
                              void* d_out, int out_size, void* d_ws, size_t ws_size,
                              hipStream_t stream) {
    (void)in_sizes; (void)n_in; (void)out_size; (void)ws_size;
    const float* x      = (const float*)d_in[0];
    const float* dist   = (const float*)d_in[1];
    const float* path   = (const float*)d_in[2];
    const float* qkv_w  = (const float*)d_in[3];
    const float* qkv_b  = (const float*)d_in[4];
    const float* o_w    = (const float*)d_in[5];
    const float* o_b    = (const float*)d_in[6];
    float* out = (float*)d_out;

    char* ws = (char*)d_ws;
    __bf16* xb     = (__bf16*)(ws);                   // 4 MB
    __bf16* qkv_wT = (__bf16*)(ws + (4  << 20));      // 1.5 MB
    __bf16* o_wT   = (__bf16*)(ws + (6  << 20));      // 0.5 MB
    __bf16* qb     = (__bf16*)(ws + (7  << 20));      // 4 MB
    __bf16* kb     = (__bf16*)(ws + (11 << 20));      // 4 MB
    __bf16* vb     = (__bf16*)(ws + (15 << 20));      // 4 MB
    __bf16* vtb    = (__bf16*)(ws + (19 << 20));      // 4 MB
    __bf16* valsb  = (__bf16*)(ws + (23 << 20));      // 4 MB

    cvt_bf16_kernel<<<(M_ * K_ / 4 + 255) / 256, 256, 0, stream>>>(x, xb, M_ * K_ / 4);
    transpose_cvt_kernel<<<dim3(N3_ / 32, K_ / 32), 256, 0, stream>>>(qkv_w, qkv_wT, K_, N3_);
    transpose_cvt_kernel<<<dim3(E_ / 32, E_ / 32), 256, 0, stream>>>(o_w, o_wT, E_, E_);
    gemm_kernel<0><<<dim3(N3_ / 128, M_ / 128), 256, 0, stream>>>(xb, qkv_wT, qkv_b, qb, kb, vb, M_, N3_, K_);
    transpose_v_kernel<<<B_ * H_ * (S_ / 64), 256, 0, stream>>>(vb, vtb);
    attn_kernel<<<B_ * H_ * (S_ / 64), 256, 0, stream>>>(qb, kb, vtb, dist, path, valsb);
    gemm_kernel<1><<<dim3(E_ / 128, M_ / 128), 256, 0, stream>>>(valsb, o_wT, o_b, out, nullptr, nullptr, M_, E_, K_);
}